// Round 8
// baseline (120.519 us; speedup 1.0000x reference)
//
#include <hip/hip_runtime.h>
#include <hip/hip_bf16.h>

typedef __bf16 bf16x8 __attribute__((ext_vector_type(8)));
typedef __bf16 bf16x2 __attribute__((ext_vector_type(2)));
typedef float  f32x16 __attribute__((ext_vector_type(16)));

#define NTOT 8192
#define DDIM 128
#define HALFB 4096
#define CSPLIT 16
#define COLS_PER_BLK (NTOT / CSPLIT)      // 512
#define TILES_PER_BLK (COLS_PER_BLK / 32) // 16 tiles of 32 cols
#define TWO_LOG2E 2.885390081777927f      // 2 / ln(2)
#define KSIM_REPS 4                        // measurement probe: k_sim x4

// ---------------- kernel 1: row-normalize to bf16 ----------------
__global__ __launch_bounds__(256) void k_norm(const float* __restrict__ zi,
                                              const float* __restrict__ zj,
                                              __bf16* __restrict__ zh) {
    int wave = threadIdx.x >> 6;
    int lane = threadIdx.x & 63;
    int row  = blockIdx.x * 4 + wave;
    const float* src = (row < HALFB) ? (zi + (size_t)row * DDIM)
                                     : (zj + (size_t)(row - HALFB) * DDIM);
    float2 v = *(const float2*)(src + lane * 2);
    float ss = v.x * v.x + v.y * v.y;
    #pragma unroll
    for (int m = 1; m < 64; m <<= 1) ss += __shfl_xor(ss, m, 64);
    float norm = sqrtf(ss);
    float inv  = 1.0f / fmaxf(norm, 1e-8f);
    bf16x2 o;
    o[0] = (__bf16)(v.x * inv);
    o[1] = (__bf16)(v.y * inv);
    *(bf16x2*)(zh + (size_t)row * DDIM + lane * 2) = o;
}

// ---------------- kernel 2: fused sim + exp-sum + pos capture ----------------
// (identical to R7's k_sim — this round only measures it via 4x replication)
__global__ __launch_bounds__(256, 4) void k_sim(const __bf16* __restrict__ zh,
                                                float* __restrict__ part,
                                                float* __restrict__ posv) {
    __shared__ char bbuf[2][8192] __attribute__((aligned(16)));

    int tid  = threadIdx.x;
    int wave = tid >> 6;
    int lane = tid & 63;
    int rowgroup = blockIdx.x / CSPLIT;
    int colblk   = blockIdx.x & (CSPLIT - 1);
    int rowbase  = rowgroup * 128 + wave * 32;   // this wave's 32 rows
    int colstart = colblk * COLS_PER_BLK;
    int l31   = lane & 31;
    int kbase = (lane >> 5) * 8;
    int hi4   = (lane >> 5) * 4;

    const char* zhb = (const char*)zh;

    // A fragments: 32 rows, in registers for the whole kernel
    bf16x8 afrag[8];
    {
        const __bf16* ap = zh + (size_t)(rowbase + l31) * DDIM + kbase;
        #pragma unroll
        for (int kk = 0; kk < 8; kk++)
            afrag[kk] = *(const bf16x8*)(ap + kk * 16);
    }

    float sumexp[16];
    #pragma unroll
    for (int r = 0; r < 16; r++) sumexp[r] = 0.0f;

    // staging addressing (tile-invariant), coalesced loads + rotated ds_write
    int kkw = (tid & 15) >> 1;
    int hw  = tid & 1;
    int c0  = tid >> 4;
    int s0c = (c0 + kkw) & 31;
    int s1c = (s0c + 16) & 31;                 // c1 = c0 + 16
    int woff0 = kkw * 1024 + hw * 512 + s0c * 16;
    int woff1 = kkw * 1024 + hw * 512 + s1c * 16;
    const char* gsrc = zhb + (size_t)colstart * 256 + tid * 16;

    int roff[8];
    #pragma unroll
    for (int kk = 0; kk < 8; kk++)
        roff[kk] = kk * 1024 + (lane >> 5) * 512 + (((l31 + kk) & 31) * 16);

    uint4 st0 = *(const uint4*)(gsrc);
    uint4 st1 = *(const uint4*)(gsrc + 4096);
    *(uint4*)((char*)bbuf + woff0) = st0;
    *(uint4*)((char*)bbuf + woff1) = st1;
    __syncthreads();

    int cur = 0;
    for (int t = 0; t < TILES_PER_BLK; t++) {
        int cbase = colstart + t * 32;
        if (t + 1 < TILES_PER_BLK) {
            const char* g = gsrc + (size_t)(t + 1) * 8192;
            st0 = *(const uint4*)(g);
            st1 = *(const uint4*)(g + 4096);
        }

        bf16x8 bfrag[8];
        const char* bb = (const char*)bbuf + (size_t)cur * 8192;
        #pragma unroll
        for (int kk = 0; kk < 8; kk++)
            bfrag[kk] = *(const bf16x8*)(bb + roff[kk]);

        f32x16 acc = {0.f,0.f,0.f,0.f,0.f,0.f,0.f,0.f,
                      0.f,0.f,0.f,0.f,0.f,0.f,0.f,0.f};
        #pragma unroll
        for (int kk = 0; kk < 8; kk++)
            acc = __builtin_amdgcn_mfma_f32_32x32x16_bf16(afrag[kk], bfrag[kk], acc, 0, 0, 0);

        if (cbase == rowbase) {
            #pragma unroll
            for (int r = 0; r < 16; r++) {
                int rl = (r & 3) + 8 * (r >> 2) + hi4;
                float e = __builtin_amdgcn_exp2f(acc[r] * TWO_LOG2E);
                sumexp[r] += (rl == l31) ? 0.0f : e;
            }
        } else if (cbase == (rowbase ^ HALFB)) {
            #pragma unroll
            for (int r = 0; r < 16; r++) {
                int rl = (r & 3) + 8 * (r >> 2) + hi4;
                sumexp[r] += __builtin_amdgcn_exp2f(acc[r] * TWO_LOG2E);
                if (rl == l31) posv[rowbase + rl] = acc[r] * 2.0f;
            }
        } else {
            #pragma unroll
            for (int r = 0; r < 16; r++)
                sumexp[r] += __builtin_amdgcn_exp2f(acc[r] * TWO_LOG2E);
        }

        if (t + 1 < TILES_PER_BLK) {
            char* w = (char*)bbuf + (size_t)(cur ^ 1) * 8192;
            *(uint4*)(w + woff0) = st0;
            *(uint4*)(w + woff1) = st1;
            __syncthreads();
            cur ^= 1;
        }
    }

    #pragma unroll
    for (int m = 1; m < 32; m <<= 1)
        #pragma unroll
        for (int r = 0; r < 16; r++)
            sumexp[r] += __shfl_xor(sumexp[r], m, 64);

    if (l31 == 0) {
        #pragma unroll
        for (int r = 0; r < 16; r++) {
            int rl  = (r & 3) + 8 * (r >> 2) + hi4;
            int row = rowbase + rl;
            part[(size_t)row * CSPLIT + colblk] = sumexp[r];
        }
    }
}

// ---------------- kernel 3: per-row loss + per-block partial sum ----------------
__global__ __launch_bounds__(256) void k_row(const float* __restrict__ part,
                                             const float* __restrict__ posv,
                                             float* __restrict__ bsum) {
    int row = blockIdx.x * 256 + threadIdx.x;
    float se = 0.0f;
    #pragma unroll
    for (int c = 0; c < CSPLIT; c++) se += part[(size_t)row * CSPLIT + c];
    float loss = __logf(se) - posv[row];
    #pragma unroll
    for (int m = 1; m < 64; m <<= 1) loss += __shfl_xor(loss, m, 64);
    __shared__ float ws[4];
    int wave = threadIdx.x >> 6, lane = threadIdx.x & 63;
    if (lane == 0) ws[wave] = loss;
    __syncthreads();
    if (threadIdx.x == 0)
        bsum[blockIdx.x] = ws[0] + ws[1] + ws[2] + ws[3];
}

// ---------------- kernel 4: final deterministic reduce + mean ----------------
__global__ void k_fin(const float* __restrict__ bsum, float* __restrict__ out) {
    int lane = threadIdx.x;  // 64 threads
    float v = (lane < 32) ? bsum[lane] : 0.0f;
    #pragma unroll
    for (int m = 1; m < 64; m <<= 1) v += __shfl_xor(v, m, 64);
    if (lane == 0) out[0] = v * (1.0f / NTOT);
}

extern "C" void kernel_launch(void* const* d_in, const int* in_sizes, int n_in,
                              void* d_out, int out_size, void* d_ws, size_t ws_size,
                              hipStream_t stream) {
    const float* zi = (const float*)d_in[0];
    const float* zj = (const float*)d_in[1];
    char* ws = (char*)d_ws;
    __bf16* zh   = (__bf16*)ws;                                   // 2 MB
    float*  part = (float*)(ws + (size_t)NTOT * DDIM * 2);        // 512 KB
    float*  posv = (float*)((char*)part + (size_t)NTOT * CSPLIT * sizeof(float)); // 32 KB
    float*  bsum = (float*)((char*)posv + (size_t)NTOT * sizeof(float));

    hipLaunchKernelGGL(k_norm, dim3(NTOT / 4), dim3(256), 0, stream, zi, zj, zh);
    // MEASUREMENT PROBE: launch k_sim KSIM_REPS times (idempotent) to make its
    // per-dispatch cost observable via dur_us arithmetic:
    //   k_sim ~= (dur_us - 40.6) / (KSIM_REPS - 1)
    for (int rep = 0; rep < KSIM_REPS; rep++)
        hipLaunchKernelGGL(k_sim, dim3((NTOT / 128) * CSPLIT), dim3(256), 0, stream, zh, part, posv);
    hipLaunchKernelGGL(k_row,  dim3(NTOT / 256), dim3(256), 0, stream, part, posv, bsum);
    hipLaunchKernelGGL(k_fin,  dim3(1), dim3(64), 0, stream, bsum, (float*)d_out);
}

// Round 9
// 40.608 us; speedup vs baseline: 2.9679x; 2.9679x over previous
//
#include <hip/hip_runtime.h>
#include <hip/hip_bf16.h>

typedef __bf16 bf16x8 __attribute__((ext_vector_type(8)));
typedef __bf16 bf16x2 __attribute__((ext_vector_type(2)));
typedef float  f32x16 __attribute__((ext_vector_type(16)));

#define NTOT 8192
#define DDIM 128
#define HALFB 4096
#define NRB 64                 // 64 row-blocks of 128 -> triangle of 2080 blocks
#define NBLK (NRB * (NRB + 1) / 2)
#define TWO_LOG2E 2.885390081777927f

// ---------------- kernel 1: row-normalize to bf16 ----------------
__global__ __launch_bounds__(256) void k_norm(const float* __restrict__ zi,
                                              const float* __restrict__ zj,
                                              __bf16* __restrict__ zh) {
    int wave = threadIdx.x >> 6;
    int lane = threadIdx.x & 63;
    int row  = blockIdx.x * 4 + wave;
    const float* src = (row < HALFB) ? (zi + (size_t)row * DDIM)
                                     : (zj + (size_t)(row - HALFB) * DDIM);
    float2 v = *(const float2*)(src + lane * 2);
    float ss = v.x * v.x + v.y * v.y;
    #pragma unroll
    for (int m = 1; m < 64; m <<= 1) ss += __shfl_xor(ss, m, 64);
    float norm = sqrtf(ss);
    float inv  = 1.0f / fmaxf(norm, 1e-8f);
    bf16x2 o;
    o[0] = (__bf16)(v.x * inv);
    o[1] = (__bf16)(v.y * inv);
    *(bf16x2*)(zh + (size_t)row * DDIM + lane * 2) = o;
}

// ---------------- kernel 2: SYMMETRIC triangular sim + exp sums ----------------
// Upper-triangle 128x128 blocks (bi<=bj). Each exp credited to its row-sum and
// (for bi<bj) its column-sum. part[row][64]: row r in rowblock b gets row-sums
// at slots b..63 (from blocks (b,bj)) and col-sums at slots 0..b-1 (from
// blocks (bi',b)) -> every slot written exactly once.
// B-panel (128 cols = 128 zh rows = 32 KB) staged whole, R7-verified swizzle.
__global__ __launch_bounds__(256, 4) void k_sim(const __bf16* __restrict__ zh,
                                                float* __restrict__ part,
                                                float* __restrict__ posv) {
    __shared__ char  bbuf[32768] __attribute__((aligned(16)));
    __shared__ float colbuf[4][128];

    int tid  = threadIdx.x;
    int wave = tid >> 6;
    int lane = tid & 63;
    int l31  = lane & 31;
    int kbase = (lane >> 5) * 8;
    int hi4   = (lane >> 5) * 4;

    // linear block id -> (bi, bj) in upper triangle
    int q = blockIdx.x, bi = 0;
    while (q >= NRB - bi) { q -= NRB - bi; bi++; }
    int bj = bi + q;
    bool db = (bi == bj);          // diagonal block: full tile, mask i==j, no col path
    bool pb = (bj == bi + 32);     // positive block: cols = rows + 4096
    int Rbase = bi * 128, Cbase = bj * 128;
    int rowbase = Rbase + 32 * wave;   // this wave's 32 rows

    const char* zhb = (const char*)zh;

    // A fragments: 32 rows in registers
    bf16x8 afrag[8];
    {
        const __bf16* ap = zh + (size_t)(rowbase + l31) * DDIM + kbase;
        #pragma unroll
        for (int kk = 0; kk < 8; kk++)
            afrag[kk] = *(const bf16x8*)(ap + kk * 16);
    }

    // stage the whole 32 KB B panel (4 sub-tiles of 8 KB, R7 swizzle per tile)
    int kkw = (tid & 15) >> 1;
    int hw  = tid & 1;
    int c0  = tid >> 4;
    int s0c = (c0 + kkw) & 31;
    int s1c = (s0c + 16) & 31;
    int woff0 = kkw * 1024 + hw * 512 + s0c * 16;
    int woff1 = kkw * 1024 + hw * 512 + s1c * 16;
    const char* gsrc = zhb + (size_t)Cbase * 256 + tid * 16;
    uint4 st[8];
    #pragma unroll
    for (int t = 0; t < 4; t++) {
        st[2 * t]     = *(const uint4*)(gsrc + t * 8192);
        st[2 * t + 1] = *(const uint4*)(gsrc + t * 8192 + 4096);
    }
    #pragma unroll
    for (int t = 0; t < 4; t++) {
        *(uint4*)(bbuf + t * 8192 + woff0) = st[2 * t];
        *(uint4*)(bbuf + t * 8192 + woff1) = st[2 * t + 1];
    }
    __syncthreads();

    int roffbase = (lane >> 5) * 512;
    float sumexp[16];
    #pragma unroll
    for (int r = 0; r < 16; r++) sumexp[r] = 0.0f;
    float colacc[4];

    #pragma unroll
    for (int t = 0; t < 4; t++) {
        bf16x8 bfrag[8];
        const char* bb = bbuf + t * 8192;
        #pragma unroll
        for (int kk = 0; kk < 8; kk++)
            bfrag[kk] = *(const bf16x8*)(bb + kk * 1024 + roffbase + ((l31 + kk) & 31) * 16);

        f32x16 acc = {0.f,0.f,0.f,0.f,0.f,0.f,0.f,0.f,
                      0.f,0.f,0.f,0.f,0.f,0.f,0.f,0.f};
        #pragma unroll
        for (int kk = 0; kk < 8; kk++)
            acc = __builtin_amdgcn_mfma_f32_32x32x16_bf16(afrag[kk], bfrag[kk], acc, 0, 0, 0);

        float ce = 0.0f;
        if (db && t == wave) {
            // diagonal sub-tile: exclude i == j (col path unused for db)
            #pragma unroll
            for (int r = 0; r < 16; r++) {
                int rl = (r & 3) + 8 * (r >> 2) + hi4;
                float e = __builtin_amdgcn_exp2f(acc[r] * TWO_LOG2E);
                sumexp[r] += (rl == l31) ? 0.0f : e;
            }
        } else {
            #pragma unroll
            for (int r = 0; r < 16; r++) {
                float e = __builtin_amdgcn_exp2f(acc[r] * TWO_LOG2E);
                sumexp[r] += e;
                ce += e;
            }
            if (pb && t == wave) {
                // positives at local lr == lc: write both partners
                #pragma unroll
                for (int r = 0; r < 16; r++) {
                    int rl = (r & 3) + 8 * (r >> 2) + hi4;
                    if (rl == l31) {
                        float s = acc[r] * 2.0f;
                        posv[rowbase + rl]            = s;
                        posv[Cbase + 32 * wave + rl]  = s;
                    }
                }
            }
        }
        colacc[t] = ce;
    }

    // column sums (only bi < bj): combine half-waves, cross-wave via LDS
    if (!db) {
        #pragma unroll
        for (int t = 0; t < 4; t++)
            colacc[t] += __shfl_xor(colacc[t], 32, 64);
        if (lane < 32) {
            #pragma unroll
            for (int t = 0; t < 4; t++)
                colbuf[wave][t * 32 + l31] = colacc[t];
        }
    }
    __syncthreads();
    if (!db && tid < 128) {
        float s = colbuf[0][tid] + colbuf[1][tid] + colbuf[2][tid] + colbuf[3][tid];
        part[(size_t)(Cbase + tid) * 64 + bi] = s;
    }

    // row sums: reduce across the 32 column lanes (halves separate)
    #pragma unroll
    for (int m = 1; m < 32; m <<= 1)
        #pragma unroll
        for (int r = 0; r < 16; r++)
            sumexp[r] += __shfl_xor(sumexp[r], m, 64);

    if (l31 == 0) {
        #pragma unroll
        for (int r = 0; r < 16; r++) {
            int rl = (r & 3) + 8 * (r >> 2) + hi4;
            part[(size_t)(rowbase + rl) * 64 + bj] = sumexp[r];
        }
    }
}

// ---------------- kernel 3: per-row loss + per-block partial sum ----------------
__global__ __launch_bounds__(256) void k_row(const float* __restrict__ part,
                                             const float* __restrict__ posv,
                                             float* __restrict__ bsum) {
    int row = blockIdx.x * 256 + threadIdx.x;
    float se = 0.0f;
    #pragma unroll
    for (int s = 0; s < 64; s++) se += part[(size_t)row * 64 + s];
    float loss = __logf(se) - posv[row];
    #pragma unroll
    for (int m = 1; m < 64; m <<= 1) loss += __shfl_xor(loss, m, 64);
    __shared__ float ws[4];
    int wave = threadIdx.x >> 6, lane = threadIdx.x & 63;
    if (lane == 0) ws[wave] = loss;
    __syncthreads();
    if (threadIdx.x == 0)
        bsum[blockIdx.x] = ws[0] + ws[1] + ws[2] + ws[3];
}

// ---------------- kernel 4: final deterministic reduce + mean ----------------
__global__ void k_fin(const float* __restrict__ bsum, float* __restrict__ out) {
    int lane = threadIdx.x;  // 64 threads
    float v = (lane < 32) ? bsum[lane] : 0.0f;
    #pragma unroll
    for (int m = 1; m < 64; m <<= 1) v += __shfl_xor(v, m, 64);
    if (lane == 0) out[0] = v * (1.0f / NTOT);
}

extern "C" void kernel_launch(void* const* d_in, const int* in_sizes, int n_in,
                              void* d_out, int out_size, void* d_ws, size_t ws_size,
                              hipStream_t stream) {
    const float* zi = (const float*)d_in[0];
    const float* zj = (const float*)d_in[1];
    char* ws = (char*)d_ws;
    __bf16* zh   = (__bf16*)ws;                                        // 2 MB
    float*  part = (float*)(ws + (size_t)NTOT * DDIM * 2);             // 2 MB (8192 x 64)
    float*  posv = (float*)((char*)part + (size_t)NTOT * 64 * sizeof(float)); // 32 KB
    float*  bsum = (float*)((char*)posv + (size_t)NTOT * sizeof(float));

    hipLaunchKernelGGL(k_norm, dim3(NTOT / 4), dim3(256), 0, stream, zi, zj, zh);
    hipLaunchKernelGGL(k_sim,  dim3(NBLK), dim3(256), 0, stream, zh, part, posv);
    hipLaunchKernelGGL(k_row,  dim3(NTOT / 256), dim3(256), 0, stream, part, posv, bsum);
    hipLaunchKernelGGL(k_fin,  dim3(1), dim3(64), 0, stream, bsum, (float*)d_out);
}